// Round 1
// baseline (124.237 us; speedup 1.0000x reference)
//
#include <hip/hip_runtime.h>
#include <math.h>

#define N_IN 256
#define BATCH 4096

// ---------------------------------------------------------------------------
// Kernel 1: build the 256 4x4 world matrices into workspace.
// WM[n] = [[R, t],[0 0 0 1]], R = K*sin(a) + (I - uuT)*cos(a) + uuT  (Rodrigues)
// u = normalize(sigmoid(uW[n])). Done in double for numerical fidelity to the
// f32 JAX reference (cost: 256 threads, once per launch — negligible).
// ---------------------------------------------------------------------------
__global__ void build_wm_kernel(const float* __restrict__ aW,
                                const float* __restrict__ uW,
                                const float* __restrict__ tW,
                                float* __restrict__ WM) {
    int n = threadIdx.x;
    if (n >= N_IN) return;

    double a = (double)aW[n];
    double u0 = 1.0 / (1.0 + exp(-(double)uW[n * 3 + 0]));
    double u1 = 1.0 / (1.0 + exp(-(double)uW[n * 3 + 1]));
    double u2 = 1.0 / (1.0 + exp(-(double)uW[n * 3 + 2]));
    double inv_norm = 1.0 / sqrt(u0 * u0 + u1 * u1 + u2 * u2);
    double ux = u0 * inv_norm, uy = u1 * inv_norm, uz = u2 * inv_norm;

    double sa = sin(a), ca = cos(a);

    // R[i][j] = K[i][j]*sa + (eye[i][j] - u_i*u_j)*ca + u_i*u_j
    // K = [[0,-uz,uy],[uz,0,-ux],[-uy,ux,0]]
    double R00 = (1.0 - ux * ux) * ca + ux * ux;
    double R01 = -uz * sa - ux * uy * ca + ux * uy;
    double R02 =  uy * sa - ux * uz * ca + ux * uz;
    double R10 =  uz * sa - uy * ux * ca + uy * ux;
    double R11 = (1.0 - uy * uy) * ca + uy * uy;
    double R12 = -ux * sa - uy * uz * ca + uy * uz;
    double R20 = -uy * sa - uz * ux * ca + uz * ux;
    double R21 =  ux * sa - uz * uy * ca + uz * uy;
    double R22 = (1.0 - uz * uz) * ca + uz * uz;

    float* w = WM + n * 16;
    w[0]  = (float)R00; w[1]  = (float)R01; w[2]  = (float)R02; w[3]  = tW[n * 3 + 0];
    w[4]  = (float)R10; w[5]  = (float)R11; w[6]  = (float)R12; w[7]  = tW[n * 3 + 1];
    w[8]  = (float)R20; w[9]  = (float)R21; w[10] = (float)R22; w[11] = tW[n * 3 + 2];
    w[12] = 0.0f;       w[13] = 0.0f;       w[14] = 0.0f;       w[15] = 1.0f;
}

// ---------------------------------------------------------------------------
// Kernel 2: out_row = I_row (1x4) @ WM[n] (4x4), one float4 row per thread.
// Row id = ((b*N_IN + n)*4 + r)  ->  n = (row >> 2) & (N_IN-1).
// Lane i loads/stores base + i*16B: perfectly coalesced dwordx4 traffic.
// WM (16 KB) is fully L1/L2-resident -> its reads cost no HBM bandwidth.
// ---------------------------------------------------------------------------
__global__ __launch_bounds__(256) void apply_wm_kernel(
        const float4* __restrict__ I,
        const float4* __restrict__ WM,   // 256 matrices, 4 float4 rows each
        float4* __restrict__ O,
        int nrows) {
    int stride = gridDim.x * blockDim.x;
    for (int idx = blockIdx.x * blockDim.x + threadIdx.x; idx < nrows; idx += stride) {
        int n = (idx >> 2) & (N_IN - 1);
        float4 r = I[idx];
        const float4* w = WM + n * 4;
        float4 w0 = w[0], w1 = w[1], w2 = w[2], w3 = w[3];
        float4 o;
        o.x = r.x * w0.x + r.y * w1.x + r.z * w2.x + r.w * w3.x;
        o.y = r.x * w0.y + r.y * w1.y + r.z * w2.y + r.w * w3.y;
        o.z = r.x * w0.z + r.y * w1.z + r.z * w2.z + r.w * w3.z;
        o.w = r.x * w0.w + r.y * w1.w + r.z * w2.w + r.w * w3.w;
        O[idx] = o;
    }
}

extern "C" void kernel_launch(void* const* d_in, const int* in_sizes, int n_in,
                              void* d_out, int out_size, void* d_ws, size_t ws_size,
                              hipStream_t stream) {
    const float* I  = (const float*)d_in[0];   // (4096, 256, 4, 4)
    const float* aW = (const float*)d_in[1];   // (256, 1, 1)
    const float* uW = (const float*)d_in[2];   // (256, 1, 3)
    const float* tW = (const float*)d_in[3];   // (256, 1, 3)
    float* out = (float*)d_out;
    float* WM = (float*)d_ws;                  // 256 * 16 floats = 16 KB

    build_wm_kernel<<<1, N_IN, 0, stream>>>(aW, uW, tW, WM);

    int nrows = BATCH * N_IN * 4;              // 4,194,304 float4 rows
    int block = 256;
    int grid = 2048;                           // grid-stride: 8 rows/thread
    apply_wm_kernel<<<grid, block, 0, stream>>>(
        (const float4*)I, (const float4*)WM, (float4*)out, nrows);
}

// Round 3
// 120.474 us; speedup vs baseline: 1.0312x; 1.0312x over previous
//
#include <hip/hip_runtime.h>
#include <math.h>

#define N_IN 256
#define BATCH 4096
#define WM_STRIDE 20   // floats per matrix in LDS (80 B): spreads banks, keeps 16B align

// ---------------------------------------------------------------------------
// Kernel 1: build the 256 4x4 world matrices into workspace (f64 for fidelity).
// One block, 256 threads, runs once per launch — cost ~2 µs, off the hot path.
// ---------------------------------------------------------------------------
__global__ void build_wm_kernel(const float* __restrict__ aW,
                                const float* __restrict__ uW,
                                const float* __restrict__ tW,
                                float* __restrict__ WM) {
    int n = threadIdx.x;
    if (n >= N_IN) return;

    double a = (double)aW[n];
    double u0 = 1.0 / (1.0 + exp(-(double)uW[n * 3 + 0]));
    double u1 = 1.0 / (1.0 + exp(-(double)uW[n * 3 + 1]));
    double u2 = 1.0 / (1.0 + exp(-(double)uW[n * 3 + 2]));
    double inv_norm = 1.0 / sqrt(u0 * u0 + u1 * u1 + u2 * u2);
    double ux = u0 * inv_norm, uy = u1 * inv_norm, uz = u2 * inv_norm;

    double sa = sin(a), ca = cos(a);

    double R00 = (1.0 - ux * ux) * ca + ux * ux;
    double R01 = -uz * sa - ux * uy * ca + ux * uy;
    double R02 =  uy * sa - ux * uz * ca + ux * uz;
    double R10 =  uz * sa - uy * ux * ca + uy * ux;
    double R11 = (1.0 - uy * uy) * ca + uy * uy;
    double R12 = -ux * sa - uy * uz * ca + uy * uz;
    double R20 = -uy * sa - uz * ux * ca + uz * ux;
    double R21 =  ux * sa - uz * uy * ca + uz * uy;
    double R22 = (1.0 - uz * uz) * ca + uz * uz;

    float* w = WM + n * 16;
    w[0]  = (float)R00; w[1]  = (float)R01; w[2]  = (float)R02; w[3]  = tW[n * 3 + 0];
    w[4]  = (float)R10; w[5]  = (float)R11; w[6]  = (float)R12; w[7]  = tW[n * 3 + 1];
    w[8]  = (float)R20; w[9]  = (float)R21; w[10] = (float)R22; w[11] = tW[n * 3 + 2];
    w[12] = 0.0f;       w[13] = 0.0f;       w[14] = 0.0f;       w[15] = 1.0f;
}

// ---------------------------------------------------------------------------
// Kernel 2: out_row = I_row (1x4) @ WM[n] (4x4), one float4 row per thread.
// WM staged global->LDS once per block; hot loop = 2 VMEM + 4 DS per 32 B HBM,
// so the VMEM pipe only carries true HBM traffic (load I row + store O row).
// LDS matrix stride = 80 B: 16 distinct b128 addresses/wave spread banks
// (2-way aliasing = free per m136), vs 8-way at 64 B stride.
// ---------------------------------------------------------------------------
__global__ __launch_bounds__(256) void apply_wm_kernel(
        const float4* __restrict__ I,
        const float4* __restrict__ WMg,   // 256 matrices, 4 float4 rows each
        float4* __restrict__ O,
        int nrows) {
    __shared__ float wm[N_IN * WM_STRIDE];   // 20 KB

    int t = threadIdx.x;
    // Stage 256 matrices (1024 float4 rows) with 256 threads: 4 rows each.
    #pragma unroll
    for (int j = 0; j < 4; ++j) {
        int g = t + j * 256;               // row id 0..1023
        float4 v = WMg[g];
        int m = g >> 2, k = g & 3;
        *reinterpret_cast<float4*>(&wm[m * WM_STRIDE + k * 4]) = v;
    }
    __syncthreads();

    int stride = gridDim.x * blockDim.x;
    for (int idx = blockIdx.x * blockDim.x + t; idx < nrows; idx += stride) {
        int n = (idx >> 2) & (N_IN - 1);
        const float* w = &wm[n * WM_STRIDE];
        float4 r = I[idx];
        float4 w0 = *reinterpret_cast<const float4*>(w);
        float4 w1 = *reinterpret_cast<const float4*>(w + 4);
        float4 w2 = *reinterpret_cast<const float4*>(w + 8);
        float4 w3 = *reinterpret_cast<const float4*>(w + 12);
        float4 o;
        o.x = r.x * w0.x + r.y * w1.x + r.z * w2.x + r.w * w3.x;
        o.y = r.x * w0.y + r.y * w1.y + r.z * w2.y + r.w * w3.y;
        o.z = r.x * w0.z + r.y * w1.z + r.z * w2.z + r.w * w3.z;
        o.w = r.x * w0.w + r.y * w1.w + r.z * w2.w + r.w * w3.w;
        O[idx] = o;
    }
}

extern "C" void kernel_launch(void* const* d_in, const int* in_sizes, int n_in,
                              void* d_out, int out_size, void* d_ws, size_t ws_size,
                              hipStream_t stream) {
    const float* I  = (const float*)d_in[0];   // (4096, 256, 4, 4)
    const float* aW = (const float*)d_in[1];   // (256, 1, 1)
    const float* uW = (const float*)d_in[2];   // (256, 1, 3)
    const float* tW = (const float*)d_in[3];   // (256, 1, 3)
    float* out = (float*)d_out;
    float* WM = (float*)d_ws;                  // 256 * 16 floats = 16 KB

    build_wm_kernel<<<1, N_IN, 0, stream>>>(aW, uW, tW, WM);

    int nrows = BATCH * N_IN * 4;              // 4,194,304 float4 rows
    int block = 256;
    int grid = 2048;                           // 8 rows per thread, grid-stride
    apply_wm_kernel<<<grid, block, 0, stream>>>(
        (const float4*)I, (const float4*)WM, (float4*)out, nrows);
}